// Round 11
// baseline (3789.537 us; speedup 1.0000x reference)
//
#include <hip/hip_runtime.h>
#include <hip/hip_bf16.h>

#define N 8192
#define FIN 128
#define FOUT 64
#define ALPHA 0.2f
#define LOG2E 1.44269504f
#define JSPLIT 4
#define JSPAN (N / JSPLIT)    // 2048 j per block
#define RBITS 65              // LDS dword stride per bit-row (conflict-free)

typedef __attribute__((ext_vector_type(8))) short short8;
typedef __attribute__((ext_vector_type(4))) float f32x4;

static __device__ __forceinline__ unsigned fkey(float x) {
    unsigned u = __float_as_uint(x);
    return (u >> 31) ? ~u : (u | 0x80000000u);
}
static __device__ __forceinline__ float fdecode(unsigned k) {
    unsigned u = (k & 0x80000000u) ? (k & 0x7FFFFFFFu) : ~k;
    return __uint_as_float(u);
}

// ---------------- k_prep: Wh = h@W; s2 = (Wh@a1)*log2e; t2 = (Wh@a2)*log2e --------
__global__ __launch_bounds__(256) void k_prep(const float* __restrict__ h,
                                              const float* __restrict__ W,
                                              const float* __restrict__ a,
                                              float* __restrict__ Wh,
                                              float* __restrict__ s2,
                                              float* __restrict__ t2,
                                              unsigned* __restrict__ keys) {
    __shared__ float lH[16 * FIN];
    __shared__ float lW[FIN * FOUT];
    __shared__ float red[8];
    const int tid = threadIdx.x;
    const int r0 = blockIdx.x * 16;
    {
        const float4* src = (const float4*)(h + (size_t)r0 * FIN);
        float4* dst = (float4*)lH;
        for (int i = tid; i < 16 * FIN / 4; i += 256) dst[i] = src[i];
        const float4* ws_ = (const float4*)W;
        float4* dw = (float4*)lW;
        for (int i = tid; i < FIN * FOUT / 4; i += 256) dw[i] = ws_[i];
    }
    __syncthreads();
    const int wave = tid >> 6, lane = tid & 63;
    float acc[4] = {0.f, 0.f, 0.f, 0.f};
    for (int k = 0; k < FIN; ++k) {
        float wv = lW[k * FOUT + lane];
#pragma unroll
        for (int r = 0; r < 4; ++r)
            acc[r] = fmaf(lH[(wave * 4 + r) * FIN + k], wv, acc[r]);
    }
    const float a1 = a[lane], a2 = a[FOUT + lane];
    float smx = -1e30f, tmx = -1e30f;
#pragma unroll
    for (int r = 0; r < 4; ++r) {
        int row = r0 + wave * 4 + r;
        Wh[(size_t)row * FOUT + lane] = acc[r];
        float sv = acc[r] * a1, tv = acc[r] * a2;
#pragma unroll
        for (int off = 32; off; off >>= 1) {
            sv += __shfl_xor(sv, off);
            tv += __shfl_xor(tv, off);
        }
        sv *= LOG2E; tv *= LOG2E;      // pre-scale: exp(x) -> exp2(x')
        if (lane == 0) { s2[row] = sv; t2[row] = tv; }
        smx = fmaxf(smx, sv);
        tmx = fmaxf(tmx, tv);
    }
    if (lane == 0) { red[wave] = smx; red[4 + wave] = tmx; }
    __syncthreads();
    if (tid == 0) {
        float ms = fmaxf(fmaxf(red[0], red[1]), fmaxf(red[2], red[3]));
        float mt = fmaxf(fmaxf(red[4], red[5]), fmaxf(red[6], red[7]));
        atomicMax(keys + 0, fkey(ms));
        atomicMax(keys + 1, fkey(mt));
    }
}

// ---------------- k_pack: Wh fp32 -> bf16 B-fragment layout ------------------------
// B-frag (16x16x32): lane holds col n = lane&15, k = (lane>>4)*8 + e
__global__ __launch_bounds__(256) void k_pack(const float* __restrict__ Wh,
                                              __hip_bfloat16* __restrict__ WhB) {
    const int c = blockIdx.x;
    const int tn = threadIdx.x >> 6;
    const int lane = threadIdx.x & 63;
    const int quad = lane >> 4, l16 = lane & 15;
    const float* src = Wh + ((size_t)(c * 32 + quad * 8)) * FOUT + tn * 16 + l16;
    union { unsigned short u[8]; short8 v; } frag;
#pragma unroll
    for (int e = 0; e < 8; ++e) {
        __hip_bfloat16 b = __float2bfloat16(src[(size_t)e * FOUT]);
        frag.u[e] = *(unsigned short*)&b;
    }
    *(short8*)&WhB[(((size_t)c * 4 + tn) * 64 + lane) * 8] = frag.v;
}

// ---------------- k_bits: adj (fp32 0/1) -> 1 bit/entry, row-major -----------------
// Fill-shaped pure stream: 1 byte out per thread, 2 contiguous float4 reads,
// no LDS, no barriers. Byte b covers adj floats [8b, 8b+8); bit e = (f != 0).
__global__ __launch_bounds__(256) void k_bits(const float* __restrict__ adj,
                                              unsigned char* __restrict__ bits) {
    const size_t tb = (size_t)blockIdx.x * 256 + threadIdx.x;  // byte index
    const float4* src = (const float4*)adj + tb * 2;
    float4 a = src[0];
    float4 b = src[1];
    unsigned m = 0;
    m |= (a.x != 0.f) ? 1u : 0u;
    m |= (a.y != 0.f) ? 2u : 0u;
    m |= (a.z != 0.f) ? 4u : 0u;
    m |= (a.w != 0.f) ? 8u : 0u;
    m |= (b.x != 0.f) ? 16u : 0u;
    m |= (b.y != 0.f) ? 32u : 0u;
    m |= (b.z != 0.f) ? 64u : 0u;
    m |= (b.w != 0.f) ? 128u : 0u;
    bits[tb] = (unsigned char)m;
}

// ---------------- k_attn: fused mask+softmax+PV, HBM-free hot loop -----------------
// Grid (N/32, 4); block 256 = 4 waves; block = 32 rows x 2048 j.
// wave: rg=wave>>1 (row half), jh=wave&1 (j half, 32 units of 32 j).
// bits + t staged in LDS once (read-only after one barrier -> barrier-free K-loop,
// no global_load_lds -> no compiler vmcnt(0) insertions). B-frags from L2 with
// depth-2 register rotation; rg-pairs read identical B chunks -> L1 twins.
__global__ __launch_bounds__(256) void k_attn(const unsigned* __restrict__ bits,
                                              const __hip_bfloat16* __restrict__ WhB,
                                              const float* __restrict__ s2,
                                              const float* __restrict__ t2,
                                              const unsigned* __restrict__ keys,
                                              float* __restrict__ acc_ws,
                                              float* __restrict__ l_ws) {
    __shared__ unsigned bitw[32 * RBITS];   // 8.3 KB
    __shared__ float tl[JSPAN];             // 8 KB
    __shared__ float ep[4][4][64][4];       // 16 KB
    const int tid = threadIdx.x;
    const int wave = tid >> 6, lane = tid & 63;
    const int quad = lane >> 4, l16 = lane & 15;
    const int rg = wave >> 1, jh = wave & 1;
    const int i0 = blockIdx.x * 32;
    const int jb = blockIdx.y * JSPAN;

    // stage bits (32 rows x 64 dwords) + t slice
    for (int i = tid; i < 32 * 64; i += 256) {
        const int r = i >> 6, c = i & 63;
        bitw[r * RBITS + c] = bits[(size_t)(i0 + r) * (N / 32) + (jb >> 5) + c];
    }
    for (int i = tid; i < JSPAN / 4; i += 256)
        ((float4*)tl)[i] = ((const float4*)(t2 + jb))[i];
    __syncthreads();

    const float mraw = fdecode(keys[0]) + fdecode(keys[1]);
    const float mm = mraw > 0.f ? mraw : ALPHA * mraw;
    const int rrow = 16 * rg + l16;               // this lane's block-row
    const float sm = s2[i0 + rrow];
    const short8* BF = (const short8*)WhB;
    const short8 onesv = {0x3F80, 0x3F80, 0x3F80, 0x3F80, 0x3F80, 0x3F80, 0x3F80, 0x3F80};

    f32x4 acc0 = {0,0,0,0}, acc1 = {0,0,0,0}, acc2 = {0,0,0,0}, acc3 = {0,0,0,0};
    f32x4 accL = {0,0,0,0};

    short8 Bp[2][4];
#define LOADB(s, uu)                                                             \
    do {                                                                         \
        const int u_ = jh * 32 + ((uu) > 31 ? 31 : (uu));                        \
        const size_t kc_ = ((size_t)blockIdx.y * (JSPAN / 32) + u_) * 4;         \
        Bp[s][0] = BF[(kc_ + 0) * 64 + lane];                                    \
        Bp[s][1] = BF[(kc_ + 1) * 64 + lane];                                    \
        Bp[s][2] = BF[(kc_ + 2) * 64 + lane];                                    \
        Bp[s][3] = BF[(kc_ + 3) * 64 + lane];                                    \
    } while (0)

    LOADB(0, 0);
    LOADB(1, 1);
#pragma unroll 1
    for (int uu = 0; uu < 32; ++uu) {
        const int u = jh * 32 + uu;
        const unsigned bd = bitw[rrow * RBITS + u];
        const unsigned bb = (bd >> (quad * 8)) & 0xFFu;
        const float* tp = &tl[u * 32 + quad * 8];
        float4 tlo = *(const float4*)tp;
        float4 thi = *(const float4*)(tp + 4);
        union { __hip_bfloat162 h2[4]; short8 v; } af;
#pragma unroll
        for (int pp = 0; pp < 4; ++pp) {
            float t0 = (pp < 2) ? ((const float*)&tlo)[2 * pp] : ((const float*)&thi)[2 * pp - 4];
            float t1 = (pp < 2) ? ((const float*)&tlo)[2 * pp + 1] : ((const float*)&thi)[2 * pp - 3];
            float x0 = sm + t0, x1 = sm + t1;
            float le0 = fmaxf(x0, ALPHA * x0), le1 = fmaxf(x1, ALPHA * x1);
            float e0 = exp2f(le0 - mm), e1 = exp2f(le1 - mm);
            float p0 = ((bb >> (2 * pp)) & 1u) ? e0 : 0.f;      // == adj * e (adj in {0,1})
            float p1 = ((bb >> (2 * pp + 1)) & 1u) ? e1 : 0.f;
            af.h2[pp] = __float22bfloat162_rn(make_float2(p0, p1));
        }
        const int sl = uu & 1;
        acc0 = __builtin_amdgcn_mfma_f32_16x16x32_bf16(af.v, Bp[sl][0], acc0, 0, 0, 0);
        acc1 = __builtin_amdgcn_mfma_f32_16x16x32_bf16(af.v, Bp[sl][1], acc1, 0, 0, 0);
        acc2 = __builtin_amdgcn_mfma_f32_16x16x32_bf16(af.v, Bp[sl][2], acc2, 0, 0, 0);
        acc3 = __builtin_amdgcn_mfma_f32_16x16x32_bf16(af.v, Bp[sl][3], acc3, 0, 0, 0);
        accL = __builtin_amdgcn_mfma_f32_16x16x32_bf16(af.v, onesv, accL, 0, 0, 0);
        LOADB(sl, uu + 2);
    }
#undef LOADB

    // softmax denominators: accL col-uniform; row = 16*rg + quad*4 + r
    if (l16 == 0) {
#pragma unroll
        for (int r = 0; r < 4; ++r)
            atomicAdd(&l_ws[i0 + 16 * rg + quad * 4 + r], accL[r]);
    }

    // combine jh pairs via LDS, then atomicAdd (j-split blocks also add)
    *(f32x4*)&ep[wave][0][lane][0] = acc0;
    *(f32x4*)&ep[wave][1][lane][0] = acc1;
    *(f32x4*)&ep[wave][2][lane][0] = acc2;
    *(f32x4*)&ep[wave][3][lane][0] = acc3;
    __syncthreads();
    if (jh == 0) {
#pragma unroll
        for (int t = 0; t < 4; ++t) {
            f32x4 mine = *(const f32x4*)&ep[wave][t][lane][0];
            f32x4 oth  = *(const f32x4*)&ep[wave + 1][t][lane][0];
#pragma unroll
            for (int r = 0; r < 4; ++r) {
                int row = 16 * rg + quad * 4 + r;   // C/D: row=(lane>>4)*4+reg
                atomicAdd(&acc_ws[(size_t)(i0 + row) * FOUT + t * 16 + l16],
                          mine[r] + oth[r]);
            }
        }
    }
}

// ---------------- k_final: out = elu(acc/l) ---------------------------------------
__global__ __launch_bounds__(256) void k_final(const float* __restrict__ acc_ws,
                                               const float* __restrict__ l_ws,
                                               float* __restrict__ out) {
    const int idx = blockIdx.x * 256 + threadIdx.x;   // one float4 per thread
    const int row = idx >> 4;                          // 16 float4 per row
    const float inv = 1.0f / l_ws[row];
    float4 a = ((const float4*)acc_ws)[idx];
    float4 o;
#pragma unroll
    for (int r = 0; r < 4; ++r) {
        float v = ((const float*)&a)[r] * inv;
        ((float*)&o)[r] = v > 0.f ? v : (exp2f(v * LOG2E) - 1.f);
    }
    ((float4*)out)[idx] = o;
}

extern "C" void kernel_launch(void* const* d_in, const int* in_sizes, int n_in,
                              void* d_out, int out_size, void* d_ws, size_t ws_size,
                              hipStream_t stream) {
    const float* h   = (const float*)d_in[0];
    const float* adj = (const float*)d_in[1];
    const float* W   = (const float*)d_in[2];
    const float* a   = (const float*)d_in[3];
    float* out = (float*)d_out;

    char* base = (char*)d_ws;
    float* Wh = (float*)base;                        base += (size_t)N * FOUT * 4;
    __hip_bfloat16* WhB = (__hip_bfloat16*)base;     base += (size_t)N * FOUT * 2;
    float* s2 = (float*)base;                        base += (size_t)N * 4;
    float* t2 = (float*)base;                        base += (size_t)N * 4;
    unsigned char* bits = (unsigned char*)base;      base += (size_t)N * N / 8;
    float* acc_ws = (float*)base;                    base += (size_t)N * FOUT * 4;
    float* l_ws = (float*)base;                      base += (size_t)N * 4;
    unsigned* keys = (unsigned*)base;

    hipMemsetAsync(acc_ws, 0, ((size_t)N * FOUT + N) * 4 + 2 * sizeof(unsigned), stream);
    k_prep<<<N / 16, 256, 0, stream>>>(h, W, a, Wh, s2, t2, keys);
    k_pack<<<N / 32, 256, 0, stream>>>(Wh, WhB);
    k_bits<<<(int)((size_t)N * N / 8 / 256), 256, 0, stream>>>(adj, bits);
    dim3 ag(N / 32, JSPLIT);
    k_attn<<<ag, 256, 0, stream>>>((const unsigned*)bits, WhB, s2, t2, keys, acc_ws, l_ws);
    k_final<<<N * FOUT / 4 / 256, 256, 0, stream>>>(acc_ws, l_ws, out);
}

// Round 12
// 424.550 us; speedup vs baseline: 8.9260x; 8.9260x over previous
//
#include <hip/hip_runtime.h>
#include <hip/hip_bf16.h>

#define N 8192
#define FIN 128
#define FOUT 64
#define ALPHA 0.2f
#define LOG2E 1.44269504f
#define JSPLIT 4
#define JSPAN (N / JSPLIT)    // 2048 j per block
#define RBITS 65              // LDS dword stride per bit-row (conflict-free)

typedef __attribute__((ext_vector_type(8))) short short8;
typedef __attribute__((ext_vector_type(4))) float f32x4;

static __device__ __forceinline__ unsigned fkey(float x) {
    unsigned u = __float_as_uint(x);
    return (u >> 31) ? ~u : (u | 0x80000000u);
}
static __device__ __forceinline__ float fdecode(unsigned k) {
    unsigned u = (k & 0x80000000u) ? (k & 0x7FFFFFFFu) : ~k;
    return __uint_as_float(u);
}

// ---------------- k_prep: Wh = h@W; s2 = (Wh@a1)*log2e; t2 = (Wh@a2)*log2e --------
__global__ __launch_bounds__(256) void k_prep(const float* __restrict__ h,
                                              const float* __restrict__ W,
                                              const float* __restrict__ a,
                                              float* __restrict__ Wh,
                                              float* __restrict__ s2,
                                              float* __restrict__ t2,
                                              unsigned* __restrict__ keys) {
    __shared__ float lH[16 * FIN];
    __shared__ float lW[FIN * FOUT];
    __shared__ float red[8];
    const int tid = threadIdx.x;
    const int r0 = blockIdx.x * 16;
    {
        const float4* src = (const float4*)(h + (size_t)r0 * FIN);
        float4* dst = (float4*)lH;
        for (int i = tid; i < 16 * FIN / 4; i += 256) dst[i] = src[i];
        const float4* ws_ = (const float4*)W;
        float4* dw = (float4*)lW;
        for (int i = tid; i < FIN * FOUT / 4; i += 256) dw[i] = ws_[i];
    }
    __syncthreads();
    const int wave = tid >> 6, lane = tid & 63;
    float acc[4] = {0.f, 0.f, 0.f, 0.f};
    for (int k = 0; k < FIN; ++k) {
        float wv = lW[k * FOUT + lane];
#pragma unroll
        for (int r = 0; r < 4; ++r)
            acc[r] = fmaf(lH[(wave * 4 + r) * FIN + k], wv, acc[r]);
    }
    const float a1 = a[lane], a2 = a[FOUT + lane];
    float smx = -1e30f, tmx = -1e30f;
#pragma unroll
    for (int r = 0; r < 4; ++r) {
        int row = r0 + wave * 4 + r;
        Wh[(size_t)row * FOUT + lane] = acc[r];
        float sv = acc[r] * a1, tv = acc[r] * a2;
#pragma unroll
        for (int off = 32; off; off >>= 1) {
            sv += __shfl_xor(sv, off);
            tv += __shfl_xor(tv, off);
        }
        sv *= LOG2E; tv *= LOG2E;      // pre-scale: exp(x) -> exp2(x')
        if (lane == 0) { s2[row] = sv; t2[row] = tv; }
        smx = fmaxf(smx, sv);
        tmx = fmaxf(tmx, tv);
    }
    if (lane == 0) { red[wave] = smx; red[4 + wave] = tmx; }
    __syncthreads();
    if (tid == 0) {
        float ms = fmaxf(fmaxf(red[0], red[1]), fmaxf(red[2], red[3]));
        float mt = fmaxf(fmaxf(red[4], red[5]), fmaxf(red[6], red[7]));
        atomicMax(keys + 0, fkey(ms));
        atomicMax(keys + 1, fkey(mt));
    }
}

// ---------------- k_pack: Wh fp32 -> bf16 B-fragment layout ------------------------
// B-frag (16x16x32): lane holds col n = lane&15, k = (lane>>4)*8 + e
__global__ __launch_bounds__(256) void k_pack(const float* __restrict__ Wh,
                                              __hip_bfloat16* __restrict__ WhB) {
    const int c = blockIdx.x;
    const int tn = threadIdx.x >> 6;
    const int lane = threadIdx.x & 63;
    const int quad = lane >> 4, l16 = lane & 15;
    const float* src = Wh + ((size_t)(c * 32 + quad * 8)) * FOUT + tn * 16 + l16;
    union { unsigned short u[8]; short8 v; } frag;
#pragma unroll
    for (int e = 0; e < 8; ++e) {
        __hip_bfloat16 b = __float2bfloat16(src[(size_t)e * FOUT]);
        frag.u[e] = *(unsigned short*)&b;
    }
    *(short8*)&WhB[(((size_t)c * 4 + tn) * 64 + lane) * 8] = frag.v;
}

// ---------------- k_bits: adj (fp32 0/1) -> 1 bit/entry, row-major -----------------
// Fill-shaped pure stream: 1 byte out per thread, 2 contiguous float4 reads.
__global__ __launch_bounds__(256) void k_bits(const float* __restrict__ adj,
                                              unsigned char* __restrict__ bits) {
    const size_t tb = (size_t)blockIdx.x * 256 + threadIdx.x;  // byte index
    const float4* src = (const float4*)adj + tb * 2;
    float4 a = src[0];
    float4 b = src[1];
    unsigned m = 0;
    m |= (a.x != 0.f) ? 1u : 0u;
    m |= (a.y != 0.f) ? 2u : 0u;
    m |= (a.z != 0.f) ? 4u : 0u;
    m |= (a.w != 0.f) ? 8u : 0u;
    m |= (b.x != 0.f) ? 16u : 0u;
    m |= (b.y != 0.f) ? 32u : 0u;
    m |= (b.z != 0.f) ? 64u : 0u;
    m |= (b.w != 0.f) ? 128u : 0u;
    bits[tb] = (unsigned char)m;
}

// ---------------- k_attn: fused mask+softmax+PV, HBM-free hot loop -----------------
// Grid (N/32, 4); block 256 = 4 waves; block = 32 rows x 2048 j.
// wave: rg=wave>>1 (row half), jh=wave&1 (j half, 32 units of 32 j).
// bits + t LDS-resident (read-only after one barrier -> barrier-free K-loop).
// B-frags from L2, depth-2 register rotation with STATIC slot indices only
// (R11 lesson: dynamic register-array indexing -> scratch/select explosion).
__global__ __launch_bounds__(256) void k_attn(const unsigned* __restrict__ bits,
                                              const __hip_bfloat16* __restrict__ WhB,
                                              const float* __restrict__ s2,
                                              const float* __restrict__ t2,
                                              const unsigned* __restrict__ keys,
                                              float* __restrict__ acc_ws,
                                              float* __restrict__ l_ws) {
    __shared__ unsigned bitw[32 * RBITS];   // 8.3 KB
    __shared__ float tl[JSPAN];             // 8 KB
    __shared__ float ep[4][4][64][4];       // 16 KB
    const int tid = threadIdx.x;
    const int wave = tid >> 6, lane = tid & 63;
    const int quad = lane >> 4, l16 = lane & 15;
    const int rg = wave >> 1, jh = wave & 1;
    const int i0 = blockIdx.x * 32;
    const int jb = blockIdx.y * JSPAN;

    // stage bits (32 rows x 64 dwords) + t slice
    for (int i = tid; i < 32 * 64; i += 256) {
        const int r = i >> 6, c = i & 63;
        bitw[r * RBITS + c] = bits[(size_t)(i0 + r) * (N / 32) + (jb >> 5) + c];
    }
    for (int i = tid; i < JSPAN / 4; i += 256)
        ((float4*)tl)[i] = ((const float4*)(t2 + jb))[i];
    __syncthreads();

    const float mraw = fdecode(keys[0]) + fdecode(keys[1]);
    const float mm = mraw > 0.f ? mraw : ALPHA * mraw;
    const int rrow = 16 * rg + l16;               // this lane's block-row
    const float sm = s2[i0 + rrow];
    const short8* BF = (const short8*)WhB;
    const short8 onesv = {0x3F80, 0x3F80, 0x3F80, 0x3F80, 0x3F80, 0x3F80, 0x3F80, 0x3F80};

    f32x4 acc0 = {0,0,0,0}, acc1 = {0,0,0,0}, acc2 = {0,0,0,0}, acc3 = {0,0,0,0};
    f32x4 accL = {0,0,0,0};

    short8 Bp0[4], Bp1[4];   // two slots, STATIC names only

#define LOADB0(uu)                                                               \
    do {                                                                         \
        const int u_ = jh * 32 + ((uu) > 31 ? 31 : (uu));                        \
        const size_t kc_ = ((size_t)blockIdx.y * (JSPAN / 32) + u_) * 4;         \
        Bp0[0] = BF[(kc_ + 0) * 64 + lane];                                      \
        Bp0[1] = BF[(kc_ + 1) * 64 + lane];                                      \
        Bp0[2] = BF[(kc_ + 2) * 64 + lane];                                      \
        Bp0[3] = BF[(kc_ + 3) * 64 + lane];                                      \
    } while (0)
#define LOADB1(uu)                                                               \
    do {                                                                         \
        const int u_ = jh * 32 + ((uu) > 31 ? 31 : (uu));                        \
        const size_t kc_ = ((size_t)blockIdx.y * (JSPAN / 32) + u_) * 4;         \
        Bp1[0] = BF[(kc_ + 0) * 64 + lane];                                      \
        Bp1[1] = BF[(kc_ + 1) * 64 + lane];                                      \
        Bp1[2] = BF[(kc_ + 2) * 64 + lane];                                      \
        Bp1[3] = BF[(kc_ + 3) * 64 + lane];                                      \
    } while (0)
#define PROC(BP, uu)                                                             \
    do {                                                                         \
        const int u_ = jh * 32 + (uu);                                           \
        const unsigned bd = bitw[rrow * RBITS + u_];                             \
        const unsigned bb = (bd >> (quad * 8)) & 0xFFu;                          \
        const float* tp = &tl[u_ * 32 + quad * 8];                               \
        float4 tlo = *(const float4*)tp;                                         \
        float4 thi = *(const float4*)(tp + 4);                                   \
        union { __hip_bfloat162 h2[4]; short8 v; } af;                           \
        _Pragma("unroll")                                                        \
        for (int pp = 0; pp < 4; ++pp) {                                         \
            float t0 = (pp < 2) ? ((const float*)&tlo)[2 * pp]                   \
                                : ((const float*)&thi)[2 * pp - 4];              \
            float t1 = (pp < 2) ? ((const float*)&tlo)[2 * pp + 1]               \
                                : ((const float*)&thi)[2 * pp - 3];              \
            float x0 = sm + t0, x1 = sm + t1;                                    \
            float le0 = fmaxf(x0, ALPHA * x0), le1 = fmaxf(x1, ALPHA * x1);      \
            float e0 = exp2f(le0 - mm), e1 = exp2f(le1 - mm);                    \
            float p0 = ((bb >> (2 * pp)) & 1u) ? e0 : 0.f;                       \
            float p1 = ((bb >> (2 * pp + 1)) & 1u) ? e1 : 0.f;                   \
            af.h2[pp] = __float22bfloat162_rn(make_float2(p0, p1));              \
        }                                                                        \
        acc0 = __builtin_amdgcn_mfma_f32_16x16x32_bf16(af.v, BP[0], acc0, 0, 0, 0); \
        acc1 = __builtin_amdgcn_mfma_f32_16x16x32_bf16(af.v, BP[1], acc1, 0, 0, 0); \
        acc2 = __builtin_amdgcn_mfma_f32_16x16x32_bf16(af.v, BP[2], acc2, 0, 0, 0); \
        acc3 = __builtin_amdgcn_mfma_f32_16x16x32_bf16(af.v, BP[3], acc3, 0, 0, 0); \
        accL = __builtin_amdgcn_mfma_f32_16x16x32_bf16(af.v, onesv, accL, 0, 0, 0); \
    } while (0)

    LOADB0(0);
    LOADB1(1);
#pragma unroll 1
    for (int k = 0; k < 16; ++k) {
        PROC(Bp0, 2 * k);
        PROC(Bp1, 2 * k + 1);
        LOADB0(2 * k + 2);      // refill for iter k+1 (clamped tail: L2-hot reread)
        LOADB1(2 * k + 3);
    }
#undef LOADB0
#undef LOADB1
#undef PROC

    // softmax denominators: accL col-uniform; row = 16*rg + quad*4 + r
    if (l16 == 0) {
#pragma unroll
        for (int r = 0; r < 4; ++r)
            atomicAdd(&l_ws[i0 + 16 * rg + quad * 4 + r], accL[r]);
    }

    // combine jh pairs via LDS, then atomicAdd (j-split blocks also add)
    *(f32x4*)&ep[wave][0][lane][0] = acc0;
    *(f32x4*)&ep[wave][1][lane][0] = acc1;
    *(f32x4*)&ep[wave][2][lane][0] = acc2;
    *(f32x4*)&ep[wave][3][lane][0] = acc3;
    __syncthreads();
    if (jh == 0) {
#pragma unroll
        for (int t = 0; t < 4; ++t) {
            f32x4 mine = *(const f32x4*)&ep[wave][t][lane][0];
            f32x4 oth  = *(const f32x4*)&ep[wave + 1][t][lane][0];
#pragma unroll
            for (int r = 0; r < 4; ++r) {
                int row = 16 * rg + quad * 4 + r;   // C/D: row=(lane>>4)*4+reg
                atomicAdd(&acc_ws[(size_t)(i0 + row) * FOUT + t * 16 + l16],
                          mine[r] + oth[r]);
            }
        }
    }
}

// ---------------- k_final: out = elu(acc/l) ---------------------------------------
__global__ __launch_bounds__(256) void k_final(const float* __restrict__ acc_ws,
                                               const float* __restrict__ l_ws,
                                               float* __restrict__ out) {
    const int idx = blockIdx.x * 256 + threadIdx.x;   // one float4 per thread
    const int row = idx >> 4;                          // 16 float4 per row
    const float inv = 1.0f / l_ws[row];
    float4 a = ((const float4*)acc_ws)[idx];
    float4 o;
#pragma unroll
    for (int r = 0; r < 4; ++r) {
        float v = ((const float*)&a)[r] * inv;
        ((float*)&o)[r] = v > 0.f ? v : (exp2f(v * LOG2E) - 1.f);
    }
    ((float4*)out)[idx] = o;
}

extern "C" void kernel_launch(void* const* d_in, const int* in_sizes, int n_in,
                              void* d_out, int out_size, void* d_ws, size_t ws_size,
                              hipStream_t stream) {
    const float* h   = (const float*)d_in[0];
    const float* adj = (const float*)d_in[1];
    const float* W   = (const float*)d_in[2];
    const float* a   = (const float*)d_in[3];
    float* out = (float*)d_out;

    char* base = (char*)d_ws;
    float* Wh = (float*)base;                        base += (size_t)N * FOUT * 4;
    __hip_bfloat16* WhB = (__hip_bfloat16*)base;     base += (size_t)N * FOUT * 2;
    float* s2 = (float*)base;                        base += (size_t)N * 4;
    float* t2 = (float*)base;                        base += (size_t)N * 4;
    unsigned char* bits = (unsigned char*)base;      base += (size_t)N * N / 8;
    float* acc_ws = (float*)base;                    base += (size_t)N * FOUT * 4;
    float* l_ws = (float*)base;                      base += (size_t)N * 4;
    unsigned* keys = (unsigned*)base;

    hipMemsetAsync(acc_ws, 0, ((size_t)N * FOUT + N) * 4 + 2 * sizeof(unsigned), stream);
    k_prep<<<N / 16, 256, 0, stream>>>(h, W, a, Wh, s2, t2, keys);
    k_pack<<<N / 32, 256, 0, stream>>>(Wh, WhB);
    k_bits<<<(int)((size_t)N * N / 8 / 256), 256, 0, stream>>>(adj, bits);
    dim3 ag(N / 32, JSPLIT);
    k_attn<<<ag, 256, 0, stream>>>((const unsigned*)bits, WhB, s2, t2, keys, acc_ws, l_ws);
    k_final<<<N * FOUT / 4 / 256, 256, 0, stream>>>(acc_ws, l_ws, out);
}